// Round 7
// baseline (151.216 us; speedup 1.0000x reference)
//
#include <hip/hip_runtime.h>
#include <hip/hip_bf16.h>

// GConv: out = relu( Agg(support) + x@loop_W + bias )
// R6: staged pipeline. GEMM n-quarter k produces sup/outv cols [64k,64k+64);
//     agg of feature-quarter k-1 runs in the SAME dispatch (disjoint columns).
//     S1{gemm_n0|scatter} S2{gemm_n1|agg_f0} ... S5{agg_f3}.
//     agg quarter working set = 2.56MB -> fits per-XCD L2 (was 10.2MB thrash).

#define NN 10000
#define DK 256
#define DO 256
#define MT 20000      // B*N rows
#define SCAN_T 1024
#define SCAN_C 10     // 10240 >= NN
#define GQ 313        // gemm m-tiles per stage (64-row tiles over 20000 rows)
#define AGB 1250      // agg blocks per stage: 5000 waves x (2 rows x 2 batches)

typedef short short8 __attribute__((ext_vector_type(8)));
typedef float f32x4 __attribute__((ext_vector_type(4)));

__device__ inline unsigned short f2bf(float f) {
    unsigned int u = __float_as_uint(f);
    u = (u + 0x7FFFu + ((u >> 16) & 1u)) >> 16;   // round-nearest-even
    return (unsigned short)u;
}
__device__ inline float bf2f(unsigned short s) {
    return __uint_as_float(((unsigned int)s) << 16);
}

// ---------------- prep: blocks [0,32) transpose W/LW -> bf16 [col][k]; rest: row histogram ----------------
__global__ __launch_bounds__(256) void prep_kernel(
    const float* __restrict__ W, const float* __restrict__ LW,
    unsigned short* __restrict__ Wt, unsigned short* __restrict__ LWt,
    const int* __restrict__ rows, int* __restrict__ counts, int E)
{
    __shared__ float tile[64][65];
    const int bid = blockIdx.x;
    if (bid < 32) {
        const int z = bid >> 4, rem = bid & 15;
        const int k0 = (rem >> 2) * 64, c0 = (rem & 3) * 64;
        const float* src = z ? LW : W;
        unsigned short* dst = z ? LWt : Wt;
        #pragma unroll
        for (int it = 0; it < 16; ++it) {
            const int u = it * 256 + threadIdx.x;
            const int i = u >> 6, j = u & 63;
            tile[i][j] = src[(size_t)(k0 + i) * DO + c0 + j];
        }
        __syncthreads();
        #pragma unroll
        for (int it = 0; it < 16; ++it) {
            const int u = it * 256 + threadIdx.x;
            const int j = u >> 6, i = u & 63;
            dst[(size_t)(c0 + j) * DK + k0 + i] = f2bf(tile[i][j]);
        }
    } else {
        const int e = (bid - 32) * 256 + threadIdx.x;
        if (e < E) atomicAdd(&counts[rows[e]], 1);
    }
}

// ---------------- scan: exclusive prefix over counts -> offsets, cursor ----------------
__global__ __launch_bounds__(SCAN_T) void scan_rows(
    const int* __restrict__ counts, int* __restrict__ offsets,
    int* __restrict__ cursor)
{
    __shared__ int sums[SCAN_T];
    const int t = threadIdx.x;
    int local[SCAN_C];
    int s = 0;
    const int base = t * SCAN_C;
    #pragma unroll
    for (int i = 0; i < SCAN_C; ++i) {
        const int idx = base + i;
        const int c = (idx < NN) ? counts[idx] : 0;
        local[i] = s;
        s += c;
    }
    sums[t] = s;
    __syncthreads();
    for (int off = 1; off < SCAN_T; off <<= 1) {
        int u = (t >= off) ? sums[t - off] : 0;
        __syncthreads();
        sums[t] += u;
        __syncthreads();
    }
    const int excl = (t == 0) ? 0 : sums[t - 1];
    #pragma unroll
    for (int i = 0; i < SCAN_C; ++i) {
        const int idx = base + i;
        if (idx < NN) {
            const int o = excl + local[i];
            offsets[idx] = o;
            cursor[idx]  = o;
        }
    }
}

// ---------------- stage kernel ----------------
// blocks [0,nGemm): dual GEMM for n-block nq (cols nq*64..+64), all 20000 rows.
// blocks [nGemm,..): extraMode 0 = edge scatter; 1 = agg+ReLU of feature-block fq.
__global__ __launch_bounds__(256) void stage_kernel(
    const float* __restrict__ X, const unsigned short* __restrict__ Wt,
    const unsigned short* __restrict__ LWt, const float* __restrict__ bias,
    unsigned short* __restrict__ sup, float* __restrict__ outv,
    const int* __restrict__ rows, const int* __restrict__ cols,
    const float* __restrict__ vals, int* __restrict__ cursor,
    float2* __restrict__ epack, const int* __restrict__ offsets,
    const int* __restrict__ counts, int E,
    int nGemm, int nq, int fq, int extraMode)
{
    __shared__ unsigned short As[8][64][8];
    __shared__ unsigned short BsW[8][64][8];
    __shared__ unsigned short BsL[8][64][8];

    if ((int)blockIdx.x >= nGemm) {
        const int ebid = blockIdx.x - nGemm;
        if (extraMode == 0) {
            // ---- edge scatter ----
            const int e = ebid * 256 + threadIdx.x;
            if (e < E) {
                const int p = atomicAdd(&cursor[rows[e]], 1);
                epack[p] = make_float2(__int_as_float(cols[e]), vals[e]);
            }
            return;
        }
        // ---- agg + ReLU for feature-quarter fq ----
        // wave = 2 rows x 2 batches x 64 feats; sub = lane>>4 -> (rsel, b)
        const int wid = threadIdx.x >> 6, lane = threadIdx.x & 63;
        const int widx = ebid * 4 + wid;            // [0, 5000)
        if (widx >= NN / 2) return;
        const int sub = lane >> 4;
        const int rsel = sub >> 1, b = sub & 1;
        const int r = widx * 2 + rsel;
        const int f0 = fq * 64 + (lane & 15) * 4;
        const int start = offsets[r];
        const int deg   = counts[r];
        const size_t supb = (size_t)b * NN * DO + f0;

        float a0 = 0.f, a1 = 0.f, a2 = 0.f, a3 = 0.f;
        #pragma unroll 8
        for (int i = 0; i < deg; ++i) {             // per-lane trip count; exec-masked
            const float2 ep = epack[start + i];
            const int col = __float_as_int(ep.x);
            const float v = ep.y;
            const ushort4 s = *(const ushort4*)&sup[supb + (size_t)col * DO];
            a0 += v * bf2f(s.x); a1 += v * bf2f(s.y);
            a2 += v * bf2f(s.z); a3 += v * bf2f(s.w);
        }

        float* o = &outv[((size_t)b * NN + r) * DO + f0];
        float4 t4 = *(const float4*)o;
        t4.x = fmaxf(t4.x + a0, 0.f); t4.y = fmaxf(t4.y + a1, 0.f);
        t4.z = fmaxf(t4.z + a2, 0.f); t4.w = fmaxf(t4.w + a3, 0.f);
        *(float4*)o = t4;
        return;
    }

    // ---- dual GEMM, 64x64 tile, n-block fixed to nq ----
    const int t = threadIdx.x;
    const int wid = t >> 6, lane = t & 63;
    const int wm = wid >> 1, wn = wid & 1;
    const int m0 = blockIdx.x * 64;
    const int n0 = nq * 64;

    f32x4 accW[2][2], accL[2][2];
    #pragma unroll
    for (int i = 0; i < 2; ++i)
        #pragma unroll
        for (int j = 0; j < 2; ++j) {
            accW[i][j] = (f32x4){0.f, 0.f, 0.f, 0.f};
            accL[i][j] = (f32x4){0.f, 0.f, 0.f, 0.f};
        }

    for (int k0 = 0; k0 < DK; k0 += 64) {
        #pragma unroll
        for (int it = 0; it < 2; ++it) {          // stage A (f32 -> bf16)
            const int u = it * 256 + t;
            const int row = u >> 3, kg = u & 7;
            const int grow = m0 + row;
            short8 v = (short8){0,0,0,0,0,0,0,0};
            if (grow < MT) {
                const float4 a = *(const float4*)&X[(size_t)grow * DK + k0 + kg * 8];
                const float4 b = *(const float4*)&X[(size_t)grow * DK + k0 + kg * 8 + 4];
                v[0] = (short)f2bf(a.x); v[1] = (short)f2bf(a.y);
                v[2] = (short)f2bf(a.z); v[3] = (short)f2bf(a.w);
                v[4] = (short)f2bf(b.x); v[5] = (short)f2bf(b.y);
                v[6] = (short)f2bf(b.z); v[7] = (short)f2bf(b.w);
            }
            *(short8*)&As[kg][row ^ kg][0] = v;
        }
        {                                          // stage B tiles (64 cols)
            const int u = t;                       // 256 threads cover 64x8/2
            const int col = u >> 2, kg2 = (u & 3) * 2;
            const size_t off = (size_t)(n0 + col) * DK + k0 + kg2 * 8;
            *(short8*)&BsW[kg2][col ^ kg2][0]           = *(const short8*)&Wt[off];
            *(short8*)&BsW[kg2 + 1][col ^ (kg2 + 1)][0] = *(const short8*)&Wt[off + 8];
            *(short8*)&BsL[kg2][col ^ kg2][0]           = *(const short8*)&LWt[off];
            *(short8*)&BsL[kg2 + 1][col ^ (kg2 + 1)][0] = *(const short8*)&LWt[off + 8];
        }
        __syncthreads();
        #pragma unroll
        for (int s = 0; s < 2; ++s) {             // two k=32 substeps
            const int kg = s * 4 + (lane >> 4);
            short8 af[2], bW[2], bL[2];
            #pragma unroll
            for (int i = 0; i < 2; ++i) {
                const int row = wm * 32 + i * 16 + (lane & 15);
                af[i] = *(const short8*)&As[kg][row ^ kg][0];
            }
            #pragma unroll
            for (int j = 0; j < 2; ++j) {
                const int col = wn * 32 + j * 16 + (lane & 15);
                bW[j] = *(const short8*)&BsW[kg][col ^ kg][0];
                bL[j] = *(const short8*)&BsL[kg][col ^ kg][0];
            }
            #pragma unroll
            for (int i = 0; i < 2; ++i)
                #pragma unroll
                for (int j = 0; j < 2; ++j) {
                    accW[i][j] = __builtin_amdgcn_mfma_f32_16x16x32_bf16(
                        af[i], bW[j], accW[i][j], 0, 0, 0);
                    accL[i][j] = __builtin_amdgcn_mfma_f32_16x16x32_bf16(
                        af[i], bL[j], accL[i][j], 0, 0, 0);
                }
        }
        __syncthreads();
    }

    const int rbase = m0 + wm * 32;
    const int cbase = n0 + wn * 32;
    #pragma unroll
    for (int i = 0; i < 2; ++i)
        #pragma unroll
        for (int q = 0; q < 4; ++q) {
            const int row = rbase + i * 16 + (lane >> 4) * 4 + q;
            if (row < MT) {
                #pragma unroll
                for (int j = 0; j < 2; ++j) {
                    const int col = cbase + j * 16 + (lane & 15);
                    sup[(size_t)row * DO + col] = f2bf(accW[i][j][q]);
                    outv[(size_t)row * DO + col] = accL[i][j][q] + bias[col];
                }
            }
        }
}

extern "C" void kernel_launch(void* const* d_in, const int* in_sizes, int n_in,
                              void* d_out, int out_size, void* d_ws, size_t ws_size,
                              hipStream_t stream)
{
    const float* x    = (const float*)d_in[0];
    const float* W    = (const float*)d_in[1];
    const float* LW   = (const float*)d_in[2];
    const float* bias = (const float*)d_in[3];
    const float* ev   = (const float*)d_in[4];
    const int*   rows = (const int*)d_in[5];
    const int*   cols = (const int*)d_in[6];
    float* out = (float*)d_out;

    const int E = in_sizes[4];
    const int EB = (E + 255) / 256;

    // workspace layout
    char* wsb = (char*)d_ws;
    unsigned short* Wt    = (unsigned short*)wsb;              // 131,072 B
    unsigned short* LWt   = (unsigned short*)(wsb + 131072);   // 131,072 B
    unsigned short* supb  = (unsigned short*)(wsb + 262144);   // 10,240,000 B
    int* counts  = (int*)(wsb + 10502144);                     // 40,000 B
    int* offsets = (int*)(wsb + 10542144);                     // 40,000 B
    int* cursor  = (int*)(wsb + 10582144);                     // 40,000 B
    float2* epack = (float2*)(wsb + 10622144);                 // 8*E B

    hipMemsetAsync(counts, 0, NN * sizeof(int), stream);

    prep_kernel<<<32 + EB, 256, 0, stream>>>(W, LW, Wt, LWt, rows, counts, E);
    scan_rows<<<1, SCAN_T, 0, stream>>>(counts, offsets, cursor);

    #define STAGE_ARGS x, Wt, LWt, bias, supb, out, rows, cols, ev, cursor, \
                       epack, offsets, counts, E
    // S1: gemm n-block 0 | scatter
    stage_kernel<<<GQ + EB, 256, 0, stream>>>(STAGE_ARGS, GQ, 0, -1, 0);
    // S2..S4: gemm n-block k | agg feature-block k-1
    stage_kernel<<<GQ + AGB, 256, 0, stream>>>(STAGE_ARGS, GQ, 1, 0, 1);
    stage_kernel<<<GQ + AGB, 256, 0, stream>>>(STAGE_ARGS, GQ, 2, 1, 1);
    stage_kernel<<<GQ + AGB, 256, 0, stream>>>(STAGE_ARGS, GQ, 3, 2, 1);
    // S5: agg feature-block 3 only
    stage_kernel<<<AGB, 256, 0, stream>>>(STAGE_ARGS, 0, -1, 3, 1);
    #undef STAGE_ARGS
}

// Round 8
// 133.844 us; speedup vs baseline: 1.1298x; 1.1298x over previous
//
#include <hip/hip_runtime.h>
#include <hip/hip_bf16.h>

// GConv: out = relu( Agg(support) + x@loop_W + bias )
// R7: R5 structure + (a) agg split into 4 feature-quarter dispatches
//     (2.56MB working set fits per-XCD L2), (b) 2-phase reg-staged
//     prefetch in the fused GEMM. R6's gemm n-split reverted (it 4x'd
//     A-staging, the actual GEMM bottleneck).

#define NN 10000
#define DK 256
#define DO 256
#define MT 20000      // B*N rows
#define SCAN_T 1024
#define SCAN_C 10     // 10240 >= NN

typedef short short8 __attribute__((ext_vector_type(8)));
typedef float f32x4 __attribute__((ext_vector_type(4)));

__device__ inline unsigned short f2bf(float f) {
    unsigned int u = __float_as_uint(f);
    u = (u + 0x7FFFu + ((u >> 16) & 1u)) >> 16;   // round-nearest-even
    return (unsigned short)u;
}
__device__ inline float bf2f(unsigned short s) {
    return __uint_as_float(((unsigned int)s) << 16);
}

// ---------------- prep: blocks [0,32) transpose W/LW -> bf16 [col][k]; rest: row histogram ----------------
__global__ __launch_bounds__(256) void prep_kernel(
    const float* __restrict__ W, const float* __restrict__ LW,
    unsigned short* __restrict__ Wt, unsigned short* __restrict__ LWt,
    const int* __restrict__ rows, int* __restrict__ counts, int E)
{
    __shared__ float tile[64][65];
    const int bid = blockIdx.x;
    if (bid < 32) {
        const int z = bid >> 4, rem = bid & 15;
        const int k0 = (rem >> 2) * 64, c0 = (rem & 3) * 64;
        const float* src = z ? LW : W;
        unsigned short* dst = z ? LWt : Wt;
        #pragma unroll
        for (int it = 0; it < 16; ++it) {
            const int u = it * 256 + threadIdx.x;
            const int i = u >> 6, j = u & 63;
            tile[i][j] = src[(size_t)(k0 + i) * DO + c0 + j];
        }
        __syncthreads();
        #pragma unroll
        for (int it = 0; it < 16; ++it) {
            const int u = it * 256 + threadIdx.x;
            const int j = u >> 6, i = u & 63;
            dst[(size_t)(c0 + j) * DK + k0 + i] = f2bf(tile[i][j]);
        }
    } else {
        const int e = (bid - 32) * 256 + threadIdx.x;
        if (e < E) atomicAdd(&counts[rows[e]], 1);
    }
}

// ---------------- scan: exclusive prefix over counts -> offsets, cursor ----------------
__global__ __launch_bounds__(SCAN_T) void scan_rows(
    const int* __restrict__ counts, int* __restrict__ offsets,
    int* __restrict__ cursor)
{
    __shared__ int sums[SCAN_T];
    const int t = threadIdx.x;
    int local[SCAN_C];
    int s = 0;
    const int base = t * SCAN_C;
    #pragma unroll
    for (int i = 0; i < SCAN_C; ++i) {
        const int idx = base + i;
        const int c = (idx < NN) ? counts[idx] : 0;
        local[i] = s;
        s += c;
    }
    sums[t] = s;
    __syncthreads();
    for (int off = 1; off < SCAN_T; off <<= 1) {
        int u = (t >= off) ? sums[t - off] : 0;
        __syncthreads();
        sums[t] += u;
        __syncthreads();
    }
    const int excl = (t == 0) ? 0 : sums[t - 1];
    #pragma unroll
    for (int i = 0; i < SCAN_C; ++i) {
        const int idx = base + i;
        if (idx < NN) {
            const int o = excl + local[i];
            offsets[idx] = o;
            cursor[idx]  = o;
        }
    }
}

// ---------------- main: blocks [0,gemmBlocks) fused dual GEMM (2-phase prefetch); rest: scatter ----------------
__global__ __launch_bounds__(256) void main_kernel(
    const float* __restrict__ X, const unsigned short* __restrict__ Wt,
    const unsigned short* __restrict__ LWt, const float* __restrict__ bias,
    unsigned short* __restrict__ sup, float* __restrict__ outv,
    const int* __restrict__ rows, const int* __restrict__ cols,
    const float* __restrict__ vals, int* __restrict__ cursor,
    float2* __restrict__ epack, int E, int gemmBlocks)
{
    __shared__ unsigned short As[8][64][8];
    __shared__ unsigned short BsW[8][64][8];
    __shared__ unsigned short BsL[8][64][8];

    if ((int)blockIdx.x >= gemmBlocks) {
        const int e = (blockIdx.x - gemmBlocks) * 256 + threadIdx.x;
        if (e < E) {
            const int p = atomicAdd(&cursor[rows[e]], 1);
            epack[p] = make_float2(__int_as_float(cols[e]), vals[e]);
        }
        return;
    }

    const int t = threadIdx.x;
    const int wid = t >> 6, lane = t & 63;
    const int wm = wid >> 1, wn = wid & 1;
    const int m0 = (blockIdx.x >> 2) * 64;
    const int n0 = (blockIdx.x & 3) * 64;

    // staging indices (same for A and B paths)
    const int srow0 = t >> 3, skg0 = t & 7;               // it=0
    const int srow1 = (256 + t) >> 3, skg1 = t & 7;       // it=1 (row+32)

    f32x4 accW[2][2], accL[2][2];
    #pragma unroll
    for (int i = 0; i < 2; ++i)
        #pragma unroll
        for (int j = 0; j < 2; ++j) {
            accW[i][j] = (f32x4){0.f, 0.f, 0.f, 0.f};
            accL[i][j] = (f32x4){0.f, 0.f, 0.f, 0.f};
        }

    float4 pa[2][2];
    short8 pbW[2], pbL[2];

    #define LOAD_TILE(K0)                                                        \
    {                                                                            \
        const int rows_[2] = {srow0, srow1};                                     \
        _Pragma("unroll")                                                        \
        for (int it = 0; it < 2; ++it) {                                         \
            const int grow = m0 + rows_[it];                                     \
            if (grow < MT) {                                                     \
                pa[it][0] = *(const float4*)&X[(size_t)grow * DK + (K0) + skg0 * 8];     \
                pa[it][1] = *(const float4*)&X[(size_t)grow * DK + (K0) + skg0 * 8 + 4]; \
            } else {                                                             \
                pa[it][0] = make_float4(0.f, 0.f, 0.f, 0.f);                     \
                pa[it][1] = make_float4(0.f, 0.f, 0.f, 0.f);                     \
            }                                                                    \
            const size_t boff = (size_t)(n0 + rows_[it]) * DK + (K0) + skg0 * 8; \
            pbW[it] = *(const short8*)&Wt[boff];                                 \
            pbL[it] = *(const short8*)&LWt[boff];                                \
        }                                                                        \
    }

    LOAD_TILE(0);

    for (int k = 0; k < 4; ++k) {
        // write staged regs to LDS
        {
            const int rows_[2] = {srow0, srow1};
            #pragma unroll
            for (int it = 0; it < 2; ++it) {
                short8 v;
                v[0] = (short)f2bf(pa[it][0].x); v[1] = (short)f2bf(pa[it][0].y);
                v[2] = (short)f2bf(pa[it][0].z); v[3] = (short)f2bf(pa[it][0].w);
                v[4] = (short)f2bf(pa[it][1].x); v[5] = (short)f2bf(pa[it][1].y);
                v[6] = (short)f2bf(pa[it][1].z); v[7] = (short)f2bf(pa[it][1].w);
                *(short8*)&As[skg0][rows_[it] ^ skg0][0] = v;
                *(short8*)&BsW[skg0][rows_[it] ^ skg0][0] = pbW[it];
                *(short8*)&BsL[skg0][rows_[it] ^ skg0][0] = pbL[it];
            }
        }
        __syncthreads();
        if (k < 3) LOAD_TILE((k + 1) * 64);   // prefetch next tile under compute
        #pragma unroll
        for (int s = 0; s < 2; ++s) {
            const int kg = s * 4 + (lane >> 4);
            short8 af[2], bW[2], bL[2];
            #pragma unroll
            for (int i = 0; i < 2; ++i) {
                const int row = wm * 32 + i * 16 + (lane & 15);
                af[i] = *(const short8*)&As[kg][row ^ kg][0];
            }
            #pragma unroll
            for (int j = 0; j < 2; ++j) {
                const int col = wn * 32 + j * 16 + (lane & 15);
                bW[j] = *(const short8*)&BsW[kg][col ^ kg][0];
                bL[j] = *(const short8*)&BsL[kg][col ^ kg][0];
            }
            #pragma unroll
            for (int i = 0; i < 2; ++i)
                #pragma unroll
                for (int j = 0; j < 2; ++j) {
                    accW[i][j] = __builtin_amdgcn_mfma_f32_16x16x32_bf16(
                        af[i], bW[j], accW[i][j], 0, 0, 0);
                    accL[i][j] = __builtin_amdgcn_mfma_f32_16x16x32_bf16(
                        af[i], bL[j], accL[i][j], 0, 0, 0);
                }
        }
        __syncthreads();
    }
    #undef LOAD_TILE

    const int rbase = m0 + wm * 32;
    const int cbase = n0 + wn * 32;
    #pragma unroll
    for (int i = 0; i < 2; ++i)
        #pragma unroll
        for (int q = 0; q < 4; ++q) {
            const int row = rbase + i * 16 + (lane >> 4) * 4 + q;
            if (row < MT) {
                #pragma unroll
                for (int j = 0; j < 2; ++j) {
                    const int col = cbase + j * 16 + (lane & 15);
                    sup[(size_t)row * DO + col] = f2bf(accW[i][j][q]);
                    outv[(size_t)row * DO + col] = accL[i][j][q] + bias[col];
                }
            }
        }
}

// ---------------- agg + ReLU, one feature quarter (64 cols) ----------------
// wave = 2 rows x 2 batches x 64 feats; 16-lane group per (row,batch).
__global__ __launch_bounds__(256) void agg_q(
    const unsigned short* __restrict__ sup, const float2* __restrict__ epack,
    const int* __restrict__ offsets, const int* __restrict__ counts,
    float* __restrict__ outv, int fq)
{
    const int widx = (blockIdx.x * 256 + threadIdx.x) >> 6;
    if (widx >= NN / 2) return;
    const int lane = threadIdx.x & 63;
    const int sub = lane >> 4;
    const int rsel = sub >> 1, b = sub & 1;
    const int r = widx * 2 + rsel;
    const int f0 = fq * 64 + (lane & 15) * 4;
    const int start = offsets[r];
    const int deg   = counts[r];
    const size_t supb = (size_t)b * NN * DO + f0;

    float a0 = 0.f, a1 = 0.f, a2 = 0.f, a3 = 0.f;
    #pragma unroll 8
    for (int i = 0; i < deg; ++i) {
        const float2 ep = epack[start + i];
        const int col = __float_as_int(ep.x);
        const float v = ep.y;
        const ushort4 s = *(const ushort4*)&sup[supb + (size_t)col * DO];
        a0 += v * bf2f(s.x); a1 += v * bf2f(s.y);
        a2 += v * bf2f(s.z); a3 += v * bf2f(s.w);
    }

    float* o = &outv[((size_t)b * NN + r) * DO + f0];
    float4 t4 = *(const float4*)o;
    t4.x = fmaxf(t4.x + a0, 0.f); t4.y = fmaxf(t4.y + a1, 0.f);
    t4.z = fmaxf(t4.z + a2, 0.f); t4.w = fmaxf(t4.w + a3, 0.f);
    *(float4*)o = t4;
}

extern "C" void kernel_launch(void* const* d_in, const int* in_sizes, int n_in,
                              void* d_out, int out_size, void* d_ws, size_t ws_size,
                              hipStream_t stream)
{
    const float* x    = (const float*)d_in[0];
    const float* W    = (const float*)d_in[1];
    const float* LW   = (const float*)d_in[2];
    const float* bias = (const float*)d_in[3];
    const float* ev   = (const float*)d_in[4];
    const int*   rows = (const int*)d_in[5];
    const int*   cols = (const int*)d_in[6];
    float* out = (float*)d_out;

    const int E = in_sizes[4];
    const int EB = (E + 255) / 256;
    const int gemmBlocks = ((MT + 63) / 64) * 4;    // 313*4 = 1252

    // workspace layout
    char* wsb = (char*)d_ws;
    unsigned short* Wt    = (unsigned short*)wsb;              // 131,072 B
    unsigned short* LWt   = (unsigned short*)(wsb + 131072);   // 131,072 B
    unsigned short* supb  = (unsigned short*)(wsb + 262144);   // 10,240,000 B
    int* counts  = (int*)(wsb + 10502144);                     // 40,000 B
    int* offsets = (int*)(wsb + 10542144);                     // 40,000 B
    int* cursor  = (int*)(wsb + 10582144);                     // 40,000 B
    float2* epack = (float2*)(wsb + 10622144);                 // 8*E B

    hipMemsetAsync(counts, 0, NN * sizeof(int), stream);

    prep_kernel<<<32 + EB, 256, 0, stream>>>(W, LW, Wt, LWt, rows, counts, E);
    scan_rows<<<1, SCAN_T, 0, stream>>>(counts, offsets, cursor);
    main_kernel<<<gemmBlocks + EB, 256, 0, stream>>>(
        x, Wt, LWt, bias, supb, out, rows, cols, ev, cursor, epack, E, gemmBlocks);

    const int aggBlocks = (NN / 2 * 64 + 255) / 256;   // 1250
    for (int fq = 0; fq < 4; ++fq)
        agg_q<<<aggBlocks, 256, 0, stream>>>(supb, epack, offsets, counts, out, fq);
}

// Round 9
// 123.630 us; speedup vs baseline: 1.2231x; 1.0826x over previous
//
#include <hip/hip_runtime.h>
#include <hip/hip_bf16.h>

// GConv: out = relu( Agg(support) + x@loop_W + bias )
// R8: R5 structure. GEMM staging rewritten to global_load_lds (16B) with
//     pre-swizzled per-lane GLOBAL source (LDS stays linear, ds_read keeps
//     XOR swizzle). X pre-converted to bf16 in prep (cvt|transpose|hist in
//     one dispatch). agg reverted to R5's single-dispatch form.

#define NN 10000
#define DK 256
#define DO 256
#define MT 20000      // B*N rows
#define SCAN_T 1024
#define SCAN_C 10     // 10240 >= NN
#define CVB 2500      // cvt blocks: 640000 short8 / 256

typedef short short8 __attribute__((ext_vector_type(8)));
typedef float f32x4 __attribute__((ext_vector_type(4)));

#define GLOAD_LDS(G, L) __builtin_amdgcn_global_load_lds(                 \
    (const __attribute__((address_space(1))) void*)(G),                   \
    (__attribute__((address_space(3))) void*)(L), 16, 0, 0)

__device__ inline unsigned short f2bf(float f) {
    unsigned int u = __float_as_uint(f);
    u = (u + 0x7FFFu + ((u >> 16) & 1u)) >> 16;   // round-nearest-even
    return (unsigned short)u;
}
__device__ inline float bf2f(unsigned short s) {
    return __uint_as_float(((unsigned int)s) << 16);
}

// ---------------- prep: [0,CVB) cvt X->bf16 | [CVB,CVB+32) transpose W/LW | rest hist ----------------
__global__ __launch_bounds__(256) void prep_kernel(
    const float* __restrict__ X, unsigned short* __restrict__ Xb,
    const float* __restrict__ W, const float* __restrict__ LW,
    unsigned short* __restrict__ Wt, unsigned short* __restrict__ LWt,
    const int* __restrict__ rows, int* __restrict__ counts, int E)
{
    __shared__ float tile[64][65];
    const int bid = blockIdx.x;
    if (bid < CVB) {
        const int i = bid * 256 + threadIdx.x;   // < 640000 always
        const float4 a = ((const float4*)X)[2 * i];
        const float4 b = ((const float4*)X)[2 * i + 1];
        short8 o;
        o[0] = (short)f2bf(a.x); o[1] = (short)f2bf(a.y);
        o[2] = (short)f2bf(a.z); o[3] = (short)f2bf(a.w);
        o[4] = (short)f2bf(b.x); o[5] = (short)f2bf(b.y);
        o[6] = (short)f2bf(b.z); o[7] = (short)f2bf(b.w);
        *(short8*)&Xb[(size_t)i * 8] = o;
    } else if (bid < CVB + 32) {
        const int zb = bid - CVB;
        const int z = zb >> 4, rem = zb & 15;
        const int k0 = (rem >> 2) * 64, c0 = (rem & 3) * 64;
        const float* src = z ? LW : W;
        unsigned short* dst = z ? LWt : Wt;
        #pragma unroll
        for (int it = 0; it < 16; ++it) {
            const int u = it * 256 + threadIdx.x;
            const int i = u >> 6, j = u & 63;
            tile[i][j] = src[(size_t)(k0 + i) * DO + c0 + j];
        }
        __syncthreads();
        #pragma unroll
        for (int it = 0; it < 16; ++it) {
            const int u = it * 256 + threadIdx.x;
            const int j = u >> 6, i = u & 63;
            dst[(size_t)(c0 + j) * DK + k0 + i] = f2bf(tile[i][j]);
        }
    } else {
        const int e = (bid - CVB - 32) * 256 + threadIdx.x;
        if (e < E) atomicAdd(&counts[rows[e]], 1);
    }
}

// ---------------- scan: exclusive prefix over counts -> offsets, cursor ----------------
__global__ __launch_bounds__(SCAN_T) void scan_rows(
    const int* __restrict__ counts, int* __restrict__ offsets,
    int* __restrict__ cursor)
{
    __shared__ int sums[SCAN_T];
    const int t = threadIdx.x;
    int local[SCAN_C];
    int s = 0;
    const int base = t * SCAN_C;
    #pragma unroll
    for (int i = 0; i < SCAN_C; ++i) {
        const int idx = base + i;
        const int c = (idx < NN) ? counts[idx] : 0;
        local[i] = s;
        s += c;
    }
    sums[t] = s;
    __syncthreads();
    for (int off = 1; off < SCAN_T; off <<= 1) {
        int u = (t >= off) ? sums[t - off] : 0;
        __syncthreads();
        sums[t] += u;
        __syncthreads();
    }
    const int excl = (t == 0) ? 0 : sums[t - 1];
    #pragma unroll
    for (int i = 0; i < SCAN_C; ++i) {
        const int idx = base + i;
        if (idx < NN) {
            const int o = excl + local[i];
            offsets[idx] = o;
            cursor[idx]  = o;
        }
    }
}

// ---------------- main: blocks [0,gemmBlocks) dual GEMM via global_load_lds; rest: scatter ----------------
// LDS layout [kg][r'][8] linear; content at [kg][r'] = data(row = r'^kg, kg)
// achieved by per-lane global source row = lane^kg. ds_read uses [kg][row^kg].
__global__ __launch_bounds__(256) void main_kernel(
    const unsigned short* __restrict__ Xb, const unsigned short* __restrict__ Wt,
    const unsigned short* __restrict__ LWt, const float* __restrict__ bias,
    unsigned short* __restrict__ sup, float* __restrict__ outv,
    const int* __restrict__ rows, const int* __restrict__ cols,
    const float* __restrict__ vals, int* __restrict__ cursor,
    float2* __restrict__ epack, int E, int gemmBlocks)
{
    __shared__ unsigned short Abuf[8 * 64 * 8];
    __shared__ unsigned short BbufW[8 * 64 * 8];
    __shared__ unsigned short BbufL[8 * 64 * 8];

    if ((int)blockIdx.x >= gemmBlocks) {
        const int e = (blockIdx.x - gemmBlocks) * 256 + threadIdx.x;
        if (e < E) {
            const int p = atomicAdd(&cursor[rows[e]], 1);
            epack[p] = make_float2(__int_as_float(cols[e]), vals[e]);
        }
        return;
    }

    const int t = threadIdx.x;
    const int wid = t >> 6, lane = t & 63;
    const int wm = wid >> 1, wn = wid & 1;
    const int m0 = (blockIdx.x >> 2) * 64;
    const int n0 = (blockIdx.x & 3) * 64;

    f32x4 accW[2][2], accL[2][2];
    #pragma unroll
    for (int i = 0; i < 2; ++i)
        #pragma unroll
        for (int j = 0; j < 2; ++j) {
            accW[i][j] = (f32x4){0.f, 0.f, 0.f, 0.f};
            accL[i][j] = (f32x4){0.f, 0.f, 0.f, 0.f};
        }

    for (int k0 = 0; k0 < DK; k0 += 64) {
        // stage: 2 chunks x {A, W, L} of 16B per thread, direct to LDS.
        #pragma unroll
        for (int c = 0; c < 2; ++c) {
            const int kg = c * 4 + wid;                 // wave-uniform
            const int src_r = lane ^ kg;                // pre-swizzled source
            const size_t aoff = (size_t)(m0 + src_r) * DK + k0 + kg * 8;
            const size_t boff = (size_t)(n0 + src_r) * DK + k0 + kg * 8;
            unsigned short* ldst = &Abuf[(c * 256 + wid * 64) * 8];
            GLOAD_LDS(&Xb[aoff], ldst);
            GLOAD_LDS(&Wt[boff],  &BbufW[(c * 256 + wid * 64) * 8]);
            GLOAD_LDS(&LWt[boff], &BbufL[(c * 256 + wid * 64) * 8]);
        }
        __syncthreads();
        #pragma unroll
        for (int s = 0; s < 2; ++s) {             // two k=32 substeps
            const int kg = s * 4 + (lane >> 4);
            short8 af[2], bW[2], bL[2];
            #pragma unroll
            for (int i = 0; i < 2; ++i) {
                const int row = wm * 32 + i * 16 + (lane & 15);
                af[i] = *(const short8*)&Abuf[((size_t)kg * 64 + (row ^ kg)) * 8];
            }
            #pragma unroll
            for (int j = 0; j < 2; ++j) {
                const int col = wn * 32 + j * 16 + (lane & 15);
                bW[j] = *(const short8*)&BbufW[((size_t)kg * 64 + (col ^ kg)) * 8];
                bL[j] = *(const short8*)&BbufL[((size_t)kg * 64 + (col ^ kg)) * 8];
            }
            #pragma unroll
            for (int i = 0; i < 2; ++i)
                #pragma unroll
                for (int j = 0; j < 2; ++j) {
                    accW[i][j] = __builtin_amdgcn_mfma_f32_16x16x32_bf16(
                        af[i], bW[j], accW[i][j], 0, 0, 0);
                    accL[i][j] = __builtin_amdgcn_mfma_f32_16x16x32_bf16(
                        af[i], bL[j], accL[i][j], 0, 0, 0);
                }
        }
        __syncthreads();
    }

    const int rbase = m0 + wm * 32;
    const int cbase = n0 + wn * 32;
    #pragma unroll
    for (int i = 0; i < 2; ++i)
        #pragma unroll
        for (int q = 0; q < 4; ++q) {
            const int row = rbase + i * 16 + (lane >> 4) * 4 + q;
            if (row < MT) {
                #pragma unroll
                for (int j = 0; j < 2; ++j) {
                    const int col = cbase + j * 16 + (lane & 15);
                    sup[(size_t)row * DO + col] = f2bf(accW[i][j][q]);
                    outv[(size_t)row * DO + col] = accL[i][j][q] + bias[col];
                }
            }
        }
}

// ---------------- aggregate + ReLU: one wave per (row, batch) ----------------
__global__ __launch_bounds__(256) void agg_relu(
    const unsigned short* __restrict__ sup, const float2* __restrict__ epack,
    const int* __restrict__ offsets, const int* __restrict__ counts,
    float* __restrict__ outv)
{
    const int widx = (blockIdx.x * 256 + threadIdx.x) >> 6;
    if (widx >= 2 * NN) return;
    const int lane = threadIdx.x & 63;
    const int b = widx & 1, r = widx >> 1;
    const int d = lane * 4;
    const size_t supb = (size_t)b * NN * DO + d;
    const int start = offsets[r];
    const int deg   = counts[r];

    float a0 = 0.f, a1 = 0.f, a2 = 0.f, a3 = 0.f;
    #pragma unroll 8
    for (int i = 0; i < deg; ++i) {
        const float2 ep = epack[start + i];
        const int col = __float_as_int(ep.x);
        const float v = ep.y;
        const ushort4 s = *(const ushort4*)&sup[supb + (size_t)col * DO];
        a0 += v * bf2f(s.x); a1 += v * bf2f(s.y);
        a2 += v * bf2f(s.z); a3 += v * bf2f(s.w);
    }

    float* o = &outv[((size_t)b * NN + r) * DO + d];
    float4 t4 = *(const float4*)o;
    t4.x = fmaxf(t4.x + a0, 0.f); t4.y = fmaxf(t4.y + a1, 0.f);
    t4.z = fmaxf(t4.z + a2, 0.f); t4.w = fmaxf(t4.w + a3, 0.f);
    *(float4*)o = t4;
}

extern "C" void kernel_launch(void* const* d_in, const int* in_sizes, int n_in,
                              void* d_out, int out_size, void* d_ws, size_t ws_size,
                              hipStream_t stream)
{
    const float* x    = (const float*)d_in[0];
    const float* W    = (const float*)d_in[1];
    const float* LW   = (const float*)d_in[2];
    const float* bias = (const float*)d_in[3];
    const float* ev   = (const float*)d_in[4];
    const int*   rows = (const int*)d_in[5];
    const int*   cols = (const int*)d_in[6];
    float* out = (float*)d_out;

    const int E = in_sizes[4];
    const int EB = (E + 255) / 256;
    const int gemmBlocks = ((MT + 63) / 64) * 4;    // 313*4 = 1252

    // workspace layout (Xb padded to 20032 rows: OOB tile-312 reads hit
    // deterministic ws bytes; those acc rows are discarded by the epilogue guard)
    char* wsb = (char*)d_ws;
    unsigned short* Wt    = (unsigned short*)wsb;               // 131,072 B
    unsigned short* LWt   = (unsigned short*)(wsb + 131072);    // 131,072 B
    unsigned short* Xb    = (unsigned short*)(wsb + 262144);    // 20032*256*2 = 10,256,384 B
    unsigned short* supb  = (unsigned short*)(wsb + 10518528);  // 10,240,000 B
    int* counts  = (int*)(wsb + 20758528);                      // 40,000 B
    int* offsets = (int*)(wsb + 20798528);                      // 40,000 B
    int* cursor  = (int*)(wsb + 20838528);                      // 40,000 B
    float2* epack = (float2*)(wsb + 20878528);                  // 8*E B

    hipMemsetAsync(counts, 0, NN * sizeof(int), stream);

    prep_kernel<<<CVB + 32 + EB, 256, 0, stream>>>(
        x, Xb, W, LW, Wt, LWt, rows, counts, E);
    scan_rows<<<1, SCAN_T, 0, stream>>>(counts, offsets, cursor);
    main_kernel<<<gemmBlocks + EB, 256, 0, stream>>>(
        Xb, Wt, LWt, bias, supb, out, rows, cols, ev, cursor, epack, E, gemmBlocks);

    const int aggBlocks = (2 * NN * 64 + 255) / 256;
    agg_relu<<<aggBlocks, 256, 0, stream>>>(supb, epack, offsets, counts, out);
}